// Round 1
// baseline (5595.586 us; speedup 1.0000x reference)
//
#include <hip/hip_runtime.h>
#include <math.h>

// ---------------- problem constants (match reference setup_inputs) ----------
#define NN 100000      // nodes
#define NEDGE 1600000  // directed edges
#define NFEAT 64
#define HID 32
#define NCLS 8

static constexpr float TWO_PI_Q = 1.5707963267948966f; // 2*pi*0.25

// ---------------- operator build --------------------------------------------
__global__ void deg_kernel(const int* __restrict__ src, const int* __restrict__ dst,
                           const float* __restrict__ ew, float* __restrict__ deg, int E) {
    int e = blockIdx.x * blockDim.x + threadIdx.x;
    if (e >= E) return;
    float w = 0.5f * fabsf(ew[e]);
    atomicAdd(&deg[src[e]], w);
    atomicAdd(&deg[dst[e]], w);
}

__global__ void dinv_kernel(float* __restrict__ deg, int n) {
    int i = blockIdx.x * blockDim.x + threadIdx.x;
    if (i >= n) return;
    float d = deg[i];
    deg[i] = (d > 0.0f) ? rsqrtf(fmaxf(d, 1e-12f)) : 0.0f;
}

__global__ void hcoef_kernel(const int* __restrict__ src, const int* __restrict__ dst,
                             const float* __restrict__ ew, const float* __restrict__ dinv,
                             float* __restrict__ hr, float* __restrict__ hi, int E) {
    int e = blockIdx.x * blockDim.x + threadIdx.x;
    if (e >= E) return;
    float w = ew[e];
    float nrm = -(dinv[src[e]] * (0.5f * w) * dinv[dst[e]]);
    float th = TWO_PI_Q * w;
    float s, c;
    sincosf(th, &s, &c);
    hr[e] = nrm * c;
    hi[e] = nrm * s;
}

// ---------------- complex sparse propagation (scatter + atomics) ------------
// Entry j in [0,2E): j<E -> (row=src, col=dst, hr, hi); j>=E -> (row=dst,
// col=src, hr, -hi)  [Hermitian structure of the magnetic Laplacian].
template <int F>
__global__ __launch_bounds__(256) void prop_scatter(
    const int* __restrict__ src, const int* __restrict__ dst,
    const float* __restrict__ hr, const float* __restrict__ hi,
    const float* __restrict__ ur, const float* __restrict__ ui,
    float* __restrict__ pr, float* __restrict__ pi, int E) {
    int t = blockIdx.x * blockDim.x + threadIdx.x;
    int j = t / F;
    int f = t % F;
    if (j >= 2 * E) return;
    bool fwd = (j < E);
    int e = fwd ? j : j - E;
    int r = fwd ? src[e] : dst[e];
    int c = fwd ? dst[e] : src[e];
    float cr = hr[e];
    float ci = fwd ? hi[e] : -hi[e];
    float xr = ur[(size_t)c * F + f];
    float xi = ui[(size_t)c * F + f];
    atomicAdd(&pr[(size_t)r * F + f], cr * xr - ci * xi);
    atomicAdd(&pi[(size_t)r * F + f], cr * xi + ci * xr);
}

// ---------------- fused Chebyshev GEMM + bias + complex ReLU ----------------
// out = t0@W0 + t1@W1 + (2p - t0)@W2 + b ; mask by (out_r >= 0); write y.
template <int FIN>
__global__ __launch_bounds__(256) void gemm_relu_kernel(
    const float* __restrict__ x0r, const float* __restrict__ x0i,
    const float* __restrict__ t1r, const float* __restrict__ t1i,
    const float* __restrict__ pr,  const float* __restrict__ pi,
    const float* __restrict__ W,   const float* __restrict__ b,
    float* __restrict__ yr, float* __restrict__ yi, int n) {
    __shared__ float sW[3 * FIN * HID];
    for (int idx = threadIdx.x; idx < 3 * FIN * HID; idx += 256) sW[idx] = W[idx];
    __syncthreads();
    int o = threadIdx.x & 31;
    int node = (blockIdx.x << 3) + (threadIdx.x >> 5);
    if (node >= n) return;
    const float* w0 = sW;
    const float* w1 = sW + FIN * HID;
    const float* w2 = sW + 2 * FIN * HID;
    float ar = 0.0f, ai = 0.0f;
    size_t base = (size_t)node * FIN;
#pragma unroll 8
    for (int f = 0; f < FIN; ++f) {
        float t0r = x0r[base + f], t0i = x0i[base + f];
        float a1r = t1r[base + f], a1i = t1i[base + f];
        float t2r = 2.0f * pr[base + f] - t0r;
        float t2i = 2.0f * pi[base + f] - t0i;
        float wa = w0[f * HID + o], wb = w1[f * HID + o], wc = w2[f * HID + o];
        ar += t0r * wa + a1r * wb + t2r * wc;
        ai += t0i * wa + a1i * wb + t2i * wc;
    }
    ar += b[o];
    ai += b[o];
    float m = (ar >= 0.0f) ? 1.0f : 0.0f;
    yr[(size_t)node * HID + o] = ar * m;
    yi[(size_t)node * HID + o] = ai * m;
}

// ---------------- head: 1x1 conv + log_softmax + argmax + softmax + z_norm --
__global__ __launch_bounds__(256) void head_kernel(
    const float* __restrict__ xr, const float* __restrict__ xi,
    const float* __restrict__ cw, const float* __restrict__ cb,
    float* __restrict__ out, int n) {
    __shared__ float scw[2 * HID * NCLS];
    for (int idx = threadIdx.x; idx < 2 * HID * NCLS; idx += 256) scw[idx] = cw[idx];
    __syncthreads();
    int i = blockIdx.x * 256 + threadIdx.x;
    if (i >= n) return;

    float x[2 * HID];
#pragma unroll
    for (int f = 0; f < HID; ++f) {
        x[f] = xr[(size_t)i * HID + f];
        x[HID + f] = xi[(size_t)i * HID + f];
    }
    float logits[NCLS];
#pragma unroll
    for (int o = 0; o < NCLS; ++o) logits[o] = cb[o];
#pragma unroll
    for (int f = 0; f < 2 * HID; ++f) {
        float xv = x[f];
#pragma unroll
        for (int o = 0; o < NCLS; ++o) logits[o] += xv * scw[f * NCLS + o];
    }
    float m = logits[0];
#pragma unroll
    for (int o = 1; o < NCLS; ++o) m = fmaxf(m, logits[o]);
    float ex[NCLS];
    float se = 0.0f;
#pragma unroll
    for (int o = 0; o < NCLS; ++o) { ex[o] = expf(logits[o] - m); se += ex[o]; }
    float lse = logf(se);
    float inv_se = 1.0f / se;
    int am = 0;
    float best = logits[0];
#pragma unroll
    for (int o = 1; o < NCLS; ++o) {
        if (logits[o] > best) { best = logits[o]; am = o; }
    }
    float nrm = 0.0f;
#pragma unroll
    for (int f = 0; f < 2 * HID; ++f) nrm += x[f] * x[f];
    float invn = 1.0f / fmaxf(sqrtf(nrm), 1e-12f);

    float* zn = out + (size_t)i * (2 * HID);
    float* lo = out + (size_t)n * (2 * HID) + (size_t)i * NCLS;
    float* pd = out + (size_t)n * (2 * HID + NCLS) + i;
    float* pb = out + (size_t)n * (2 * HID + NCLS + 1) + (size_t)i * NCLS;
#pragma unroll
    for (int f = 0; f < 2 * HID; ++f) zn[f] = x[f] * invn;
#pragma unroll
    for (int o = 0; o < NCLS; ++o) lo[o] = logits[o] - m - lse;
    *pd = (float)am;
#pragma unroll
    for (int o = 0; o < NCLS; ++o) pb[o] = ex[o] * inv_se;
}

// ---------------- launch -----------------------------------------------------
extern "C" void kernel_launch(void* const* d_in, const int* in_sizes, int n_in,
                              void* d_out, int out_size, void* d_ws, size_t ws_size,
                              hipStream_t stream) {
    const int N = NN;
    const int E = NEDGE;

    const float* real = (const float*)d_in[0];
    const float* imag = (const float*)d_in[1];
    const int*   eidx = (const int*)d_in[2];
    const float* ew   = (const float*)d_in[3];
    const float* W0   = (const float*)d_in[4];
    const float* b0   = (const float*)d_in[5];
    const float* W1   = (const float*)d_in[6];
    const float* b1   = (const float*)d_in[7];
    const float* W2   = (const float*)d_in[8];
    const float* b2   = (const float*)d_in[9];
    const float* cw   = (const float*)d_in[10];
    const float* cb   = (const float*)d_in[11];
    const int* src = eidx;
    const int* dst = eidx + E;

    float* p = (float*)d_ws;
    float* deg = p; p += N;
    float* hr  = p; p += E;
    float* hi  = p; p += E;
    float* Br  = p; p += (size_t)N * 64;
    float* Bi  = p; p += (size_t)N * 64;
    float* Cr  = p; p += (size_t)N * 64;
    float* Ci  = p; p += (size_t)N * 64;
    float* X0r = p; p += (size_t)N * 32;
    float* X0i = p; p += (size_t)N * 32;
    float* X1r = p; p += (size_t)N * 32;
    float* X1i = p; p += (size_t)N * 32;

    float* out = (float*)d_out;

    // ---- operator build ----
    hipMemsetAsync(deg, 0, (size_t)N * sizeof(float), stream);
    deg_kernel<<<(E + 255) / 256, 256, 0, stream>>>(src, dst, ew, deg, E);
    dinv_kernel<<<(N + 255) / 256, 256, 0, stream>>>(deg, N);
    hcoef_kernel<<<(E + 255) / 256, 256, 0, stream>>>(src, dst, ew, deg, hr, hi, E);

    // ---- layer 0: x = (real, imag), FIN = 64 -> X0 ----
    {
        constexpr int F = 64;
        size_t fb = (size_t)N * F * sizeof(float);
        long long total = (long long)2 * E * F;
        int blocks = (int)((total + 255) / 256);
        hipMemsetAsync(Br, 0, fb, stream);
        hipMemsetAsync(Bi, 0, fb, stream);
        prop_scatter<F><<<blocks, 256, 0, stream>>>(src, dst, hr, hi, real, imag, Br, Bi, E);
        hipMemsetAsync(Cr, 0, fb, stream);
        hipMemsetAsync(Ci, 0, fb, stream);
        prop_scatter<F><<<blocks, 256, 0, stream>>>(src, dst, hr, hi, Br, Bi, Cr, Ci, E);
        gemm_relu_kernel<F><<<(N + 7) / 8, 256, 0, stream>>>(real, imag, Br, Bi, Cr, Ci,
                                                             W0, b0, X0r, X0i, N);
    }
    // ---- layer 1: x = X0, FIN = 32 -> X1 ----
    {
        constexpr int F = 32;
        size_t fb = (size_t)N * F * sizeof(float);
        long long total = (long long)2 * E * F;
        int blocks = (int)((total + 255) / 256);
        hipMemsetAsync(Br, 0, fb, stream);
        hipMemsetAsync(Bi, 0, fb, stream);
        prop_scatter<F><<<blocks, 256, 0, stream>>>(src, dst, hr, hi, X0r, X0i, Br, Bi, E);
        hipMemsetAsync(Cr, 0, fb, stream);
        hipMemsetAsync(Ci, 0, fb, stream);
        prop_scatter<F><<<blocks, 256, 0, stream>>>(src, dst, hr, hi, Br, Bi, Cr, Ci, E);
        gemm_relu_kernel<F><<<(N + 7) / 8, 256, 0, stream>>>(X0r, X0i, Br, Bi, Cr, Ci,
                                                             W1, b1, X1r, X1i, N);
    }
    // ---- layer 2: x = X1, FIN = 32 -> X0 ----
    {
        constexpr int F = 32;
        size_t fb = (size_t)N * F * sizeof(float);
        long long total = (long long)2 * E * F;
        int blocks = (int)((total + 255) / 256);
        hipMemsetAsync(Br, 0, fb, stream);
        hipMemsetAsync(Bi, 0, fb, stream);
        prop_scatter<F><<<blocks, 256, 0, stream>>>(src, dst, hr, hi, X1r, X1i, Br, Bi, E);
        hipMemsetAsync(Cr, 0, fb, stream);
        hipMemsetAsync(Ci, 0, fb, stream);
        prop_scatter<F><<<blocks, 256, 0, stream>>>(src, dst, hr, hi, Br, Bi, Cr, Ci, E);
        gemm_relu_kernel<F><<<(N + 7) / 8, 256, 0, stream>>>(X1r, X1i, Br, Bi, Cr, Ci,
                                                             W2, b2, X0r, X0i, N);
    }
    // ---- head ----
    head_kernel<<<(N + 255) / 256, 256, 0, stream>>>(X0r, X0i, cw, cb, out, N);
}

// Round 5
// 2962.771 us; speedup vs baseline: 1.8886x; 1.8886x over previous
//
#include <hip/hip_runtime.h>
#include <math.h>

// ---------------- problem constants (match reference setup_inputs) ----------
#define NN 100000      // nodes
#define NEDGE 1600000  // directed edges
#define HID 32
#define NCLS 8

static constexpr float TWO_PI_Q = 1.5707963267948966f; // 2*pi*0.25

// ---------------- CSR build (deterministic: integer atomics only) -----------
// Entry j in [0,2E): j<E -> (row=src[j], col=dst[j], +sin); j>=E ->
// (row=dst[j-E], col=src[j-E], -sin)   [Hermitian magnetic Laplacian].

__global__ void count_rows(const int* __restrict__ src, const int* __restrict__ dst,
                           int* __restrict__ cnt, int E) {
    int j = blockIdx.x * blockDim.x + threadIdx.x;
    if (j >= 2 * E) return;
    int r = (j < E) ? src[j] : dst[j - E];
    atomicAdd(&cnt[r], 1);
}

#define SCAN_B 256
__global__ void scan_block_sums(const int* __restrict__ cnt, int* __restrict__ bsum, int n) {
    __shared__ int s[SCAN_B];
    int i = blockIdx.x * SCAN_B + threadIdx.x;
    s[threadIdx.x] = (i < n) ? cnt[i] : 0;
    __syncthreads();
    for (int off = SCAN_B / 2; off > 0; off >>= 1) {
        if (threadIdx.x < off) s[threadIdx.x] += s[threadIdx.x + off];
        __syncthreads();
    }
    if (threadIdx.x == 0) bsum[blockIdx.x] = s[0];
}

__global__ void scan_bsum(int* __restrict__ bsum, int nb) {  // single block, 512 thr
    __shared__ int s[512];
    int t = threadIdx.x;
    int orig = (t < nb) ? bsum[t] : 0;
    s[t] = orig;
    __syncthreads();
    for (int off = 1; off < 512; off <<= 1) {
        int v = (t >= off) ? s[t - off] : 0;
        __syncthreads();
        s[t] += v;
        __syncthreads();
    }
    if (t < nb) bsum[t] = s[t] - orig;  // exclusive
}

__global__ void scan_final(const int* __restrict__ cnt, const int* __restrict__ bsum,
                           int* __restrict__ row_ptr, int* __restrict__ cursor, int n) {
    __shared__ int s[SCAN_B];
    int t = threadIdx.x;
    int i = blockIdx.x * SCAN_B + t;
    int v = (i < n) ? cnt[i] : 0;
    s[t] = v;
    __syncthreads();
    for (int off = 1; off < SCAN_B; off <<= 1) {
        int u = (t >= off) ? s[t - off] : 0;
        __syncthreads();
        s[t] += u;
        __syncthreads();
    }
    int excl = s[t] - v + bsum[blockIdx.x];
    if (i < n) {
        row_ptr[i] = excl;
        cursor[i] = excl;
        if (i == n - 1) row_ptr[n] = excl + v;
    }
}

// Phase 1: drop entry ids at atomic-cursor positions (order ARBITRARY).
__global__ void fill_ids(const int* __restrict__ src, const int* __restrict__ dst,
                         int* __restrict__ cursor, int* __restrict__ eid_tmp, int E) {
    int j = blockIdx.x * blockDim.x + threadIdx.x;
    if (j >= 2 * E) return;
    int r = (j < E) ? src[j] : dst[j - E];
    int pos = atomicAdd(&cursor[r], 1);
    eid_tmp[pos] = j;
}

// Phase 2: canonicalize — final pos = beg + rank(id within row). Ids unique,
// so the result is the row sorted ascending by entry id, independent of the
// atomic order above. One wave per row; per-lane independent work only.
__global__ __launch_bounds__(256) void rank_scatter(
    const int* __restrict__ rp, const int* __restrict__ eid_tmp,
    int* __restrict__ eid, int n) {
    int w = (blockIdx.x * 256 + threadIdx.x) >> 6;
    if (w >= n) return;
    int lane = threadIdx.x & 63;
    int beg = rp[w], end = rp[w + 1];
    for (int p = beg + lane; p < end; p += 64) {
        int id = eid_tmp[p];
        int rank = 0;
        for (int q = beg; q < end; ++q) rank += (eid_tmp[q] < id) ? 1 : 0;
        eid[beg + rank] = id;
    }
}

// Degree from the SORTED slice: ONE THREAD per row, strictly sequential sum
// => bit-deterministic, no cross-lane primitives. Stores dinv directly.
__global__ void deg_row_seq(
    const int* __restrict__ rp, const int* __restrict__ eid,
    const float* __restrict__ ew, float* __restrict__ dinv_out, int n) {
    int w = blockIdx.x * blockDim.x + threadIdx.x;
    if (w >= n) return;
    int beg = rp[w], end = rp[w + 1];
    float d = 0.0f;
    for (int p = beg; p < end; ++p) {
        int id = eid[p];
        int e = (id < (int)NEDGE) ? id : id - (int)NEDGE;
        d += 0.5f * fabsf(ew[e]);
    }
    dinv_out[w] = (d > 0.0f) ? rsqrtf(fmaxf(d, 1e-12f)) : 0.0f;
}

// Final CSR arrays: col + complex coefficient, from sorted ids (deterministic).
__global__ __launch_bounds__(256) void coef_fill(
    const int* __restrict__ rp, const int* __restrict__ eid,
    const int* __restrict__ src, const int* __restrict__ dst,
    const float* __restrict__ ew, const float* __restrict__ dinv,
    int* __restrict__ col_s, float2* __restrict__ coef, int n) {
    int w = (blockIdx.x * 256 + threadIdx.x) >> 6;
    if (w >= n) return;
    int lane = threadIdx.x & 63;
    int beg = rp[w], end = rp[w + 1];
    float dr = dinv[w];
    for (int p = beg + lane; p < end; p += 64) {
        int id = eid[p];
        bool fwd = (id < (int)NEDGE);
        int e = fwd ? id : id - (int)NEDGE;
        int c = fwd ? dst[e] : src[e];
        float wgt = ew[e];
        float nrm = -(dr * (0.5f * wgt) * dinv[c]);
        float s, co;
        sincosf(TWO_PI_Q * wgt, &s, &co);
        col_s[p] = c;
        coef[p] = make_float2(nrm * co, fwd ? nrm * s : -nrm * s);
    }
}

// ---------------- gather propagation (no atomics, sequential => det.) -------
__global__ __launch_bounds__(256) void prop_gather64(
    const int* __restrict__ rp, const int* __restrict__ col_s,
    const float2* __restrict__ coef,
    const float* __restrict__ ur, const float* __restrict__ ui,
    float* __restrict__ pr, float* __restrict__ pi, int n) {
    int w = (blockIdx.x * 256 + threadIdx.x) >> 6;
    if (w >= n) return;
    int f = threadIdx.x & 63;
    int beg = rp[w], end = rp[w + 1];
    float accr = 0.0f, acci = 0.0f;
    for (int p = beg; p < end; ++p) {
        int c = col_s[p];
        float2 h = coef[p];
        float xr = ur[(size_t)c * 64 + f];
        float xi = ui[(size_t)c * 64 + f];
        accr += h.x * xr - h.y * xi;
        acci += h.x * xi + h.y * xr;
    }
    pr[(size_t)w * 64 + f] = accr;
    pi[(size_t)w * 64 + f] = acci;
}

// F=32: lanes 0-31 accumulate real, lanes 32-63 imag (same gathers, no diverge)
__global__ __launch_bounds__(256) void prop_gather32(
    const int* __restrict__ rp, const int* __restrict__ col_s,
    const float2* __restrict__ coef,
    const float* __restrict__ ur, const float* __restrict__ ui,
    float* __restrict__ pr, float* __restrict__ pi, int n) {
    int w = (blockIdx.x * 256 + threadIdx.x) >> 6;
    if (w >= n) return;
    int lane = threadIdx.x & 63;
    int f = lane & 31;
    int h = lane >> 5;
    int beg = rp[w], end = rp[w + 1];
    float acc = 0.0f;
    for (int p = beg; p < end; ++p) {
        int c = col_s[p];
        float2 hc = coef[p];
        float xr = ur[(size_t)c * 32 + f];
        float xi = ui[(size_t)c * 32 + f];
        float a = hc.x * xr - hc.y * xi;
        float b = hc.x * xi + hc.y * xr;
        acc += h ? b : a;
    }
    float* o = h ? pi : pr;
    o[(size_t)w * 32 + f] = acc;
}

// ---------------- fused Chebyshev GEMM + bias + complex ReLU ----------------
template <int FIN>
__global__ __launch_bounds__(256) void gemm_relu_kernel(
    const float* __restrict__ x0r, const float* __restrict__ x0i,
    const float* __restrict__ t1r, const float* __restrict__ t1i,
    const float* __restrict__ pr,  const float* __restrict__ pi,
    const float* __restrict__ W,   const float* __restrict__ b,
    float* __restrict__ yr, float* __restrict__ yi, int n) {
    __shared__ float sW[3 * FIN * HID];
    for (int idx = threadIdx.x; idx < 3 * FIN * HID; idx += 256) sW[idx] = W[idx];
    __syncthreads();
    int o = threadIdx.x & 31;
    int node = (blockIdx.x << 3) + (threadIdx.x >> 5);
    if (node >= n) return;
    const float* w0 = sW;
    const float* w1 = sW + FIN * HID;
    const float* w2 = sW + 2 * FIN * HID;
    float ar = 0.0f, ai = 0.0f;
    size_t base = (size_t)node * FIN;
#pragma unroll 8
    for (int f = 0; f < FIN; ++f) {
        float t0r = x0r[base + f], t0i = x0i[base + f];
        float a1r = t1r[base + f], a1i = t1i[base + f];
        float t2r = 2.0f * pr[base + f] - t0r;
        float t2i = 2.0f * pi[base + f] - t0i;
        float wa = w0[f * HID + o], wb = w1[f * HID + o], wc = w2[f * HID + o];
        ar += t0r * wa + a1r * wb + t2r * wc;
        ai += t0i * wa + a1i * wb + t2i * wc;
    }
    ar += b[o];
    ai += b[o];
    float m = (ar >= 0.0f) ? 1.0f : 0.0f;
    yr[(size_t)node * HID + o] = ar * m;
    yi[(size_t)node * HID + o] = ai * m;
}

// ---------------- head: 1x1 conv + log_softmax + argmax + softmax + z_norm --
__global__ __launch_bounds__(256) void head_kernel(
    const float* __restrict__ xr, const float* __restrict__ xi,
    const float* __restrict__ cw, const float* __restrict__ cb,
    float* __restrict__ out, int n) {
    __shared__ float scw[2 * HID * NCLS];
    for (int idx = threadIdx.x; idx < 2 * HID * NCLS; idx += 256) scw[idx] = cw[idx];
    __syncthreads();
    int i = blockIdx.x * 256 + threadIdx.x;
    if (i >= n) return;

    float x[2 * HID];
#pragma unroll
    for (int f = 0; f < HID; ++f) {
        x[f] = xr[(size_t)i * HID + f];
        x[HID + f] = xi[(size_t)i * HID + f];
    }
    float logits[NCLS];
#pragma unroll
    for (int o = 0; o < NCLS; ++o) logits[o] = cb[o];
#pragma unroll
    for (int f = 0; f < 2 * HID; ++f) {
        float xv = x[f];
#pragma unroll
        for (int o = 0; o < NCLS; ++o) logits[o] += xv * scw[f * NCLS + o];
    }
    float m = logits[0];
#pragma unroll
    for (int o = 1; o < NCLS; ++o) m = fmaxf(m, logits[o]);
    float ex[NCLS];
    float se = 0.0f;
#pragma unroll
    for (int o = 0; o < NCLS; ++o) { ex[o] = expf(logits[o] - m); se += ex[o]; }
    float lse = logf(se);
    float inv_se = 1.0f / se;
    int am = 0;
    float best = logits[0];
#pragma unroll
    for (int o = 1; o < NCLS; ++o) {
        if (logits[o] > best) { best = logits[o]; am = o; }
    }
    float nrm = 0.0f;
#pragma unroll
    for (int f = 0; f < 2 * HID; ++f) nrm += x[f] * x[f];
    float invn = 1.0f / fmaxf(sqrtf(nrm), 1e-12f);

    float* zn = out + (size_t)i * (2 * HID);
    float* lo = out + (size_t)n * (2 * HID) + (size_t)i * NCLS;
    float* pd = out + (size_t)n * (2 * HID + NCLS) + i;
    float* pb = out + (size_t)n * (2 * HID + NCLS + 1) + (size_t)i * NCLS;
#pragma unroll
    for (int f = 0; f < 2 * HID; ++f) zn[f] = x[f] * invn;
#pragma unroll
    for (int o = 0; o < NCLS; ++o) lo[o] = logits[o] - m - lse;
    *pd = (float)am;
#pragma unroll
    for (int o = 0; o < NCLS; ++o) pb[o] = ex[o] * inv_se;
}

// ---------------- launch -----------------------------------------------------
extern "C" void kernel_launch(void* const* d_in, const int* in_sizes, int n_in,
                              void* d_out, int out_size, void* d_ws, size_t ws_size,
                              hipStream_t stream) {
    const int N = NN;
    const int E = NEDGE;
    const int NB = (N + SCAN_B - 1) / SCAN_B;  // 391

    const float* real = (const float*)d_in[0];
    const float* imag = (const float*)d_in[1];
    const int*   eidx = (const int*)d_in[2];
    const float* ew   = (const float*)d_in[3];
    const float* W0   = (const float*)d_in[4];
    const float* b0   = (const float*)d_in[5];
    const float* W1   = (const float*)d_in[6];
    const float* b1   = (const float*)d_in[7];
    const float* W2   = (const float*)d_in[8];
    const float* b2   = (const float*)d_in[9];
    const float* cw   = (const float*)d_in[10];
    const float* cb   = (const float*)d_in[11];
    const int* src = eidx;
    const int* dst = eidx + E;

    // ---- workspace carve (float2 first for 8B alignment) ----
    char* base = (char*)d_ws;
    float2* coef  = (float2*)base;              base += (size_t)2 * E * sizeof(float2);
    int* col_s    = (int*)base;                 base += (size_t)2 * E * sizeof(int);
    int* eid      = (int*)base;                 base += (size_t)2 * E * sizeof(int);
    float* dinv   = (float*)base;               base += (size_t)N * sizeof(float);
    int* cnt      = (int*)base;                 base += (size_t)N * sizeof(int);
    int* row_ptr  = (int*)base;                 base += (size_t)(N + 1) * sizeof(int);
    int* cursor   = (int*)base;                 base += (size_t)N * sizeof(int);
    int* bsum     = (int*)base;                 base += (size_t)512 * sizeof(int);
    float* Br     = (float*)base;               base += (size_t)N * 64 * sizeof(float);
    float* Bi     = (float*)base;               base += (size_t)N * 64 * sizeof(float);
    float* Cr     = (float*)base;               base += (size_t)N * 64 * sizeof(float);
    float* Ci     = (float*)base;               base += (size_t)N * 64 * sizeof(float);
    float* X0r    = (float*)base;               base += (size_t)N * 32 * sizeof(float);
    float* X0i    = (float*)base;               base += (size_t)N * 32 * sizeof(float);
    float* X1r    = (float*)base;               base += (size_t)N * 32 * sizeof(float);
    float* X1i    = (float*)base;               base += (size_t)N * 32 * sizeof(float);
    // eid_tmp lives in Cr (N*64 floats = 25.6MB >= 12.8MB needed). Cr is first
    // written by the second prop of layer 0, long after rank_scatter consumed
    // eid_tmp. No aliasing with col_s/eid.
    int* eid_tmp = (int*)Cr;

    float* out = (float*)d_out;
    const int rowwave_blocks = (N * 64 + 255) / 256;  // one wave per row

    // ---- CSR build (deterministic) ----
    (void)hipMemsetAsync(cnt, 0, (size_t)N * sizeof(int), stream);
    count_rows<<<(2 * E + 255) / 256, 256, 0, stream>>>(src, dst, cnt, E);
    scan_block_sums<<<NB, SCAN_B, 0, stream>>>(cnt, bsum, N);
    scan_bsum<<<1, 512, 0, stream>>>(bsum, NB);
    scan_final<<<NB, SCAN_B, 0, stream>>>(cnt, bsum, row_ptr, cursor, N);
    fill_ids<<<(2 * E + 255) / 256, 256, 0, stream>>>(src, dst, cursor, eid_tmp, E);
    rank_scatter<<<rowwave_blocks, 256, 0, stream>>>(row_ptr, eid_tmp, eid, N);
    deg_row_seq<<<(N + 255) / 256, 256, 0, stream>>>(row_ptr, eid, ew, dinv, N);
    coef_fill<<<rowwave_blocks, 256, 0, stream>>>(row_ptr, eid, src, dst, ew, dinv,
                                                  col_s, coef, N);

    // ---- layer 0: x = (real, imag), F = 64 -> X0 ----
    prop_gather64<<<rowwave_blocks, 256, 0, stream>>>(row_ptr, col_s, coef, real, imag, Br, Bi, N);
    prop_gather64<<<rowwave_blocks, 256, 0, stream>>>(row_ptr, col_s, coef, Br, Bi, Cr, Ci, N);
    gemm_relu_kernel<64><<<(N + 7) / 8, 256, 0, stream>>>(real, imag, Br, Bi, Cr, Ci,
                                                          W0, b0, X0r, X0i, N);
    // ---- layer 1: x = X0, F = 32 -> X1 ----
    prop_gather32<<<rowwave_blocks, 256, 0, stream>>>(row_ptr, col_s, coef, X0r, X0i, Br, Bi, N);
    prop_gather32<<<rowwave_blocks, 256, 0, stream>>>(row_ptr, col_s, coef, Br, Bi, Cr, Ci, N);
    gemm_relu_kernel<32><<<(N + 7) / 8, 256, 0, stream>>>(X0r, X0i, Br, Bi, Cr, Ci,
                                                          W1, b1, X1r, X1i, N);
    // ---- layer 2: x = X1, F = 32 -> X0 ----
    prop_gather32<<<rowwave_blocks, 256, 0, stream>>>(row_ptr, col_s, coef, X1r, X1i, Br, Bi, N);
    prop_gather32<<<rowwave_blocks, 256, 0, stream>>>(row_ptr, col_s, coef, Br, Bi, Cr, Ci, N);
    gemm_relu_kernel<32><<<(N + 7) / 8, 256, 0, stream>>>(X1r, X1i, Br, Bi, Cr, Ci,
                                                          W2, b2, X0r, X0i, N);
    // ---- head ----
    head_kernel<<<(N + 255) / 256, 256, 0, stream>>>(X0r, X0i, cw, cb, out, N);
}